// Round 7
// baseline (350.938 us; speedup 1.0000x reference)
//
#include <hip/hip_runtime.h>

typedef unsigned short u16;
typedef unsigned int u32;
typedef __attribute__((ext_vector_type(8))) short s16x8;
typedef __attribute__((ext_vector_type(4))) float f32x4;
typedef __attribute__((ext_vector_type(4))) int i32x4;

// ---------- bf16 helpers (bit-level, RNE) ----------
static __device__ __forceinline__ float bf2f(u16 u) {
    return __uint_as_float(((u32)u) << 16);
}
static __device__ __forceinline__ u16 f2bf(float f) {
    u32 x = __float_as_uint(f);
    return (u16)((x + 0x7fffu + ((x >> 16) & 1u)) >> 16);
}
static __device__ __forceinline__ i32x4 pack8(float4 a, float4 b) {
    u32 p0 = (u32)f2bf(a.x) | ((u32)f2bf(a.y) << 16);
    u32 p1 = (u32)f2bf(a.z) | ((u32)f2bf(a.w) << 16);
    u32 p2 = (u32)f2bf(b.x) | ((u32)f2bf(b.y) << 16);
    u32 p3 = (u32)f2bf(b.z) | ((u32)f2bf(b.w) << 16);
    return (i32x4){(int)p0, (int)p1, (int)p2, (int)p3};
}
static __device__ __forceinline__ float wave_sum(float v) {
#pragma unroll
    for (int off = 32; off > 0; off >>= 1) v += __shfl_xor(v, off);
    return v;
}
// async global->LDS, 16B per lane; dest is wave-uniform base (+lane*16 by HW)
static __device__ __forceinline__ void gload16(const u16* g, void* l) {
    __builtin_amdgcn_global_load_lds((const __attribute__((address_space(1))) void*)g,
                                     (__attribute__((address_space(3))) void*)l, 16, 0, 0);
}

// ---------- fp32 -> bf16 weight conversion (8 elems/thread) ----------
__global__ __launch_bounds__(256) void cvt_bf16(const float* __restrict__ src,
                                                u16* __restrict__ dst, int n8) {
    int i = blockIdx.x * 256 + threadIdx.x;
    if (i >= n8) return;
    float4 a = *(const float4*)(src + (size_t)i * 8);
    float4 b = *(const float4*)(src + (size_t)i * 8 + 4);
    *(i32x4*)(dst + (size_t)i * 8) = pack8(a, b);
}

// ---------- out init for split-K GEMMs: out = (resid?resid:0) + gate*bias ----------
__global__ __launch_bounds__(256) void init_axpb(const float* __restrict__ resid,
                                                 const float* __restrict__ gate,
                                                 const float* __restrict__ bias,
                                                 float* __restrict__ out) {
    int i4 = blockIdx.x * 256 + threadIdx.x;  // float4 units over [2048][768]
    int base = i4 * 4;
    int col = base % 768;
    float4 r = resid ? *(const float4*)(resid + base) : (float4){0.f, 0.f, 0.f, 0.f};
    if (bias) {
        r.x += gate[col] * bias[col];
        r.y += gate[col + 1] * bias[col + 1];
        r.z += gate[col + 2] * bias[col + 2];
        r.w += gate[col + 3] * bias[col + 3];
    }
    *(float4*)(out + base) = r;
}

// ---------- adaLN: mod = silu(c) @ ada_w.T + ada_b ----------
__global__ __launch_bounds__(256) void ada_gemm(const float* __restrict__ c,
                                                const float* __restrict__ adaw,
                                                const float* __restrict__ adab,
                                                float* __restrict__ mod) {
    int wid = blockIdx.x * 4 + (threadIdx.x >> 6);
    int lane = threadIdx.x & 63;
    float sum = 0.f;
#pragma unroll
    for (int i = 0; i < 12; ++i) {
        float cv = c[i * 64 + lane];
        cv = cv / (1.f + __expf(-cv));
        sum += cv * adaw[(size_t)wid * 768 + i * 64 + lane];
    }
    sum = wave_sum(sum);
    if (lane == 0) mod[wid] = sum + adab[wid];
}

// ---------- fused RMSNorm + modulate, writes bf16 ----------
__global__ __launch_bounds__(256) void rms_mod(const float* __restrict__ x,
                                               const float* __restrict__ w,
                                               const float* __restrict__ mod, int chunk,
                                               u16* __restrict__ out) {
    const int row = blockIdx.x;
    const int tid = threadIdx.x;
    const float* xr = x + (size_t)row * 768;
    float v0 = xr[tid], v1 = xr[256 + tid], v2 = xr[512 + tid];
    float ss = wave_sum(v0 * v0 + v1 * v1 + v2 * v2);
    __shared__ float red[4];
    if ((tid & 63) == 0) red[tid >> 6] = ss;
    __syncthreads();
    float rn = rsqrtf((red[0] + red[1] + red[2] + red[3]) * (1.f / 768.f) + 1e-6f);
    const float* sh = mod + chunk * 768;
    const float* sc = sh + 768;
    u16* orow = out + (size_t)row * 768;
    orow[tid]       = f2bf(v0 * rn * w[tid]       * (1.f + sc[tid])       + sh[tid]);
    orow[256 + tid] = f2bf(v1 * rn * w[256 + tid] * (1.f + sc[256 + tid]) + sh[256 + tid]);
    orow[512 + tid] = f2bf(v2 * rn * w[512 + tid] * (1.f + sc[512 + tid]) + sh[512 + tid]);
}

// ---------- plain RMSNorm (cond), fp32 out ----------
__global__ __launch_bounds__(256) void rms_plain(const float* __restrict__ x,
                                                 const float* __restrict__ w,
                                                 float* __restrict__ out) {
    const int row = blockIdx.x;
    const int tid = threadIdx.x;
    const float* xr = x + (size_t)row * 768;
    float v0 = xr[tid], v1 = xr[256 + tid], v2 = xr[512 + tid];
    float ss = wave_sum(v0 * v0 + v1 * v1 + v2 * v2);
    __shared__ float red[4];
    if ((tid & 63) == 0) red[tid >> 6] = ss;
    __syncthreads();
    float rn = rsqrtf((red[0] + red[1] + red[2] + red[3]) * (1.f / 768.f) + 1e-6f);
    float* orow = out + (size_t)row * 768;
    orow[tid]       = v0 * rn * w[tid];
    orow[256 + tid] = v1 * rn * w[256 + tid];
    orow[512 + tid] = v2 * rn * w[512 + tid];
}

// ---------- MFMA bf16 GEMM v3: 256 thr, 128x128 tile, BK=32, XCD swizzle, split-K ----------
// C[M,N] = A[M,K](bf16) @ Wb[N,K](bf16)^T.  4 waves (2x2), per-wave 64x64 (acc[4][4]).
// 1D grid: sub = bid % nsub (spatial tile), z = bid / nsub (K-slice of kslice elems).
// XCD swizzle: xcd = sub&7 owns a CxR chunk of the (nx x ny) tile grid; nxc = chunks/row.
// EPI 0: f32 out. 1: bf16 out. 2: out = resid + gate[col]*(acc+bias[col]).
// 3: bf16(silu(acc)). 4: outb RMW *= acc. 5: atomicAdd(out, gate?gate[col]*acc:acc).
template <int EPI>
__global__ __launch_bounds__(256) void gemm_bt3(const u16* __restrict__ A,
                                                const u16* __restrict__ Wb,
                                                int M, int N, int K,
                                                float* outf, u16* outb,
                                                const float* resid,
                                                const float* __restrict__ gate,
                                                const float* __restrict__ bias,
                                                int C, int R, int nxc,
                                                int nsub, int kslice) {
    __shared__ __align__(16) u16 As[2][128 * 32];
    __shared__ __align__(16) u16 Bs[2][128 * 32];
    const int tid = threadIdx.x;
    const int lane = tid & 63;
    const int w = tid >> 6;
    const int wr = w >> 1, wc = w & 1;  // 2x2 wave grid; per-wave 64x64 out
    const int bid = blockIdx.x;
    const int sub = bid % nsub;
    const int z = bid / nsub;
    const int xcd = sub & 7, idx = sub >> 3;
    const int cx = xcd % nxc, cy = xcd / nxc;
    const int col0 = (cx * C + idx % C) << 7;
    const int row0 = (cy * R + idx / C) << 7;
    const int kbase = z * kslice;

    // staging: 512 16B-units per array; thread stages units tid and tid+256
    const int r0u = tid >> 2, s0u = (tid & 3) ^ (r0u & 3);
    const int r1u = (tid + 256) >> 2, s1u = (tid & 3) ^ (r1u & 3);
    const u16* a0 = A + (size_t)(row0 + r0u) * K + kbase + s0u * 8;
    const u16* a1 = A + (size_t)(row0 + r1u) * K + kbase + s1u * 8;
    const u16* b0 = Wb + (size_t)(col0 + r0u) * K + kbase + s0u * 8;
    const u16* b1 = Wb + (size_t)(col0 + r1u) * K + kbase + s1u * 8;

    f32x4 acc[4][4];
#pragma unroll
    for (int m = 0; m < 4; ++m)
#pragma unroll
        for (int n = 0; n < 4; ++n) acc[m][n] = (f32x4){0.f, 0.f, 0.f, 0.f};

    const int nt = kslice >> 5;
    int cur = 0;
    {
        char* ad = (char*)As[0] + w * 1024;
        char* bd = (char*)Bs[0] + w * 1024;
        gload16(a0, ad);
        gload16(a1, ad + 4096);
        gload16(b0, bd);
        gload16(b1, bd + 4096);
    }
    for (int t = 0; t < nt; ++t) {
        __syncthreads();  // tile t staged; buf cur^1 free
        if (t + 1 < nt) {
            int k0 = (t + 1) << 5;
            char* ad = (char*)As[cur ^ 1] + w * 1024;
            char* bd = (char*)Bs[cur ^ 1] + w * 1024;
            gload16(a0 + k0, ad);
            gload16(a1 + k0, ad + 4096);
            gload16(b0 + k0, bd);
            gload16(b1 + k0, bd + 4096);
        }
        s16x8 af[4], bfv[4];
#pragma unroll
        for (int m = 0; m < 4; ++m) {
            int ra = wr * 64 + m * 16 + (lane & 15);
            int u = (lane >> 4) ^ (ra & 3);
            af[m] = *(const s16x8*)((const char*)As[cur] + ra * 64 + u * 16);
        }
#pragma unroll
        for (int n = 0; n < 4; ++n) {
            int cb = wc * 64 + n * 16 + (lane & 15);
            int u = (lane >> 4) ^ (cb & 3);
            bfv[n] = *(const s16x8*)((const char*)Bs[cur] + cb * 64 + u * 16);
        }
#pragma unroll
        for (int m = 0; m < 4; ++m)
#pragma unroll
            for (int n = 0; n < 4; ++n)
                acc[m][n] = __builtin_amdgcn_mfma_f32_16x16x32_bf16(af[m], bfv[n], acc[m][n], 0, 0, 0);
        cur ^= 1;
    }
    // epilogue: C frag map col=lane&15, row=(lane>>4)*4+i (HW-verified)
#pragma unroll
    for (int m = 0; m < 4; ++m) {
#pragma unroll
        for (int n = 0; n < 4; ++n) {
#pragma unroll
            for (int i = 0; i < 4; ++i) {
                int r = row0 + wr * 64 + m * 16 + (lane >> 4) * 4 + i;
                int cc = col0 + wc * 64 + n * 16 + (lane & 15);
                size_t idx2 = (size_t)r * N + cc;
                float v = acc[m][n][i];
                if constexpr (EPI == 0) {
                    outf[idx2] = v;
                } else if constexpr (EPI == 1) {
                    outb[idx2] = f2bf(v);
                } else if constexpr (EPI == 2) {
                    float b = bias ? bias[cc] : 0.f;
                    outf[idx2] = resid[idx2] + gate[cc] * (v + b);
                } else if constexpr (EPI == 3) {
                    outb[idx2] = f2bf(v / (1.f + __expf(-v)));
                } else if constexpr (EPI == 4) {
                    outb[idx2] = f2bf(v * bf2f(outb[idx2]));
                } else if constexpr (EPI == 5) {
                    atomicAdd(&outf[idx2], gate ? gate[cc] * v : v);
                }
            }
        }
    }
}

// ---------- SA q/k: RMSNorm(head) + RoPE, in place on qkv bf16 ----------
__global__ __launch_bounds__(256) void saqk_rmsrope(u16* __restrict__ qkv,
                                                    const float* __restrict__ qnw,
                                                    const float* __restrict__ knw,
                                                    const float* __restrict__ cosT,
                                                    const float* __restrict__ sinT) {
    int wid = blockIdx.x * 4 + (threadIdx.x >> 6);  // 0..49151
    int lane = threadIdx.x & 63;
    int n = wid / 24;
    int rem = wid % 24;
    int which = rem / 12;  // 0=q 1=k
    int h = rem % 12;
    u16* p = qkv + (size_t)n * 2304 + which * 768 + h * 64 + lane;
    float v = bf2f(*p);
    float ss = wave_sum(v * v);
    const float* wv = which ? knw : qnw;
    float vn = v * rsqrtf(ss * (1.f / 64.f) + 1e-6f) * wv[lane];
    float part = __shfl_xor(vn, 32);
    float rot = (lane < 32) ? -part : part;
    *p = f2bf(vn * cosT[n * 64 + lane] + rot * sinT[n * 64 + lane]);
}

// ---------- V transpose: qkv V part [2048][12*64] -> vT [12][64][2048] ----------
__global__ __launch_bounds__(256) void v_transpose(const u16* __restrict__ qkv,
                                                   u16* __restrict__ vT) {
    const int kt = blockIdx.x, h = blockIdx.y;
    const int tid = threadIdx.x;
    __shared__ __align__(16) u16 tt[64][72];  // +8 pad breaks bank conflicts
    {
        int key = tid >> 2, qq = tid & 3;
        const u16* src = qkv + (size_t)(kt * 64 + key) * 2304 + 1536 + h * 64 + qq * 16;
        *(i32x4*)&tt[key][qq * 16]     = *(const i32x4*)src;
        *(i32x4*)&tt[key][qq * 16 + 8] = *(const i32x4*)(src + 8);
    }
    __syncthreads();
    {
        int d = tid >> 2, kq = tid & 3;
        s16x8 o0, o1;
#pragma unroll
        for (int e = 0; e < 8; ++e) o0[e] = (short)tt[kq * 16 + e][d];
#pragma unroll
        for (int e = 0; e < 8; ++e) o1[e] = (short)tt[kq * 16 + 8 + e][d];
        u16* dst = vT + (size_t)h * 131072 + (size_t)d * 2048 + kt * 64 + kq * 16;
        *(s16x8*)dst = o0;
        *(s16x8*)(dst + 8) = o1;
    }
}

// ---------- SA flash attention, MFMA bf16, FIXED-MAX softmax + 2-way key split ----------
__global__ __launch_bounds__(256) void sa_attn_mfma(const u16* __restrict__ qkv,
                                                    const u16* __restrict__ vT,
                                                    u16* __restrict__ po0,
                                                    u16* __restrict__ po1,
                                                    float* __restrict__ pl) {
    const int h = blockIdx.y;
    const int r0 = blockIdx.x * 64;
    const int z = blockIdx.z;  // key split
    const int tid = threadIdx.x;
    const int lane = tid & 63;
    const int w = tid >> 6;
    __shared__ __align__(16) u16 Ks[2][64 * 64];
    __shared__ __align__(16) u16 Vs[2][64 * 64];
    __shared__ __align__(16) u16 Ps[4][16 * 64];

    s16x8 qf[2];
    {
        const u16* qrow = qkv + (size_t)(r0 + w * 16 + (lane & 15)) * 2304 + h * 64 + ((lane >> 4) * 8);
        qf[0] = *(const s16x8*)qrow;
        qf[1] = *(const s16x8*)(qrow + 32);
    }
    f32x4 oacc[4];
#pragma unroll
    for (int n = 0; n < 4; ++n) oacc[n] = (f32x4){0.f, 0.f, 0.f, 0.f};
    float lp[4] = {0.f, 0.f, 0.f, 0.f};

    const u16* ksrc[2];
    const u16* vsrc[2];
#pragma unroll
    for (int j = 0; j < 2; ++j) {
        int u = (w * 2 + j) * 64 + lane;
        int row = u >> 3, seg = (u & 7) ^ (row & 7);
        ksrc[j] = qkv + (size_t)(z * 1024 + row) * 2304 + 768 + h * 64 + seg * 8;
        vsrc[j] = vT + (size_t)h * 131072 + (size_t)row * 2048 + z * 1024 + seg * 8;
    }

#define SA_STAGE(buf, t_)                                          \
    {                                                              \
        char* kd = (char*)Ks[buf] + w * 2048;                      \
        char* vd = (char*)Vs[buf] + w * 2048;                      \
        gload16(ksrc[0] + (size_t)(t_) * 147456, kd);              \
        gload16(ksrc[1] + (size_t)(t_) * 147456, kd + 1024);       \
        gload16(vsrc[0] + (t_) * 64, vd);                          \
        gload16(vsrc[1] + (t_) * 64, vd + 1024);                   \
    }

    SA_STAGE(0, 0)
    int cur = 0;
    for (int t = 0; t < 16; ++t) {
        __syncthreads();
        if (t + 1 < 16) SA_STAGE(cur ^ 1, t + 1)

        f32x4 sacc[4];
#pragma unroll
        for (int n = 0; n < 4; ++n) sacc[n] = (f32x4){0.f, 0.f, 0.f, 0.f};
#pragma unroll
        for (int kk = 0; kk < 2; ++kk) {
#pragma unroll
            for (int n = 0; n < 4; ++n) {
                int key = n * 16 + (lane & 15);
                int d = kk * 32 + (lane >> 4) * 8;
                int boff = key * 128 + ((d * 2) ^ ((key & 7) << 4));
                s16x8 kf = *(const s16x8*)((const char*)Ks[cur] + boff);
                sacc[n] = __builtin_amdgcn_mfma_f32_16x16x32_bf16(qf[kk], kf, sacc[n], 0, 0, 0);
            }
        }
        // fixed-max softmax: p = exp(s*0.125 - 8); |s*0.125| <= 8 by Cauchy-Schwarz
#pragma unroll
        for (int n = 0; n < 4; ++n) {
#pragma unroll
            for (int i = 0; i < 4; ++i) {
                float p = __expf(fmaf(sacc[n][i], 0.125f, -8.0f));
                lp[i] += p;
                int row = (lane >> 4) * 4 + i;
                int key = n * 16 + (lane & 15);
                int boff = row * 128 + ((key * 2) ^ ((row & 7) << 4));
                *(u16*)((char*)Ps[w] + boff) = f2bf(p);
            }
        }
#pragma unroll
        for (int kk = 0; kk < 2; ++kk) {
            int koff = kk * 32 + (lane >> 4) * 8;
            int prow = lane & 15;
            int pboff = prow * 128 + ((koff * 2) ^ ((prow & 7) << 4));
            s16x8 pf = *(const s16x8*)((const char*)Ps[w] + pboff);
#pragma unroll
            for (int n = 0; n < 4; ++n) {
                int d = n * 16 + (lane & 15);
                int vboff = d * 128 + ((koff * 2) ^ ((d & 7) << 4));
                s16x8 vf = *(const s16x8*)((const char*)Vs[cur] + vboff);
                oacc[n] = __builtin_amdgcn_mfma_f32_16x16x32_bf16(pf, vf, oacc[n], 0, 0, 0);
            }
        }
        cur ^= 1;
    }
#undef SA_STAGE
#pragma unroll
    for (int off = 1; off < 16; off <<= 1) {
#pragma unroll
        for (int i = 0; i < 4; ++i) lp[i] += __shfl_xor(lp[i], off);
    }
    u16* po = z ? po1 : po0;
#pragma unroll
    for (int n = 0; n < 4; ++n) {
#pragma unroll
        for (int i = 0; i < 4; ++i) {
            int r = r0 + w * 16 + (lane >> 4) * 4 + i;
            int d = n * 16 + (lane & 15);
            po[(size_t)r * 768 + h * 64 + d] = f2bf(oacc[n][i]);
        }
    }
    if ((lane & 15) == 0) {
#pragma unroll
        for (int i = 0; i < 4; ++i) {
            int r = r0 + w * 16 + (lane >> 4) * 4 + i;
            pl[z * 24576 + h * 2048 + r] = lp[i];
        }
    }
}

// ---------- combine the two key-split partials: O = (Oa+Ob)/(la+lb) ----------
__global__ __launch_bounds__(256) void sa_combine(const u16* __restrict__ pa,
                                                  const u16* __restrict__ pb,
                                                  const float* __restrict__ pl,
                                                  u16* __restrict__ obuf) {
    int idx = blockIdx.x * 256 + threadIdx.x;  // 8-elem units
    int base = idx * 8;
    int row = base / 768;
    int col = base % 768;
    int h = col >> 6;
    float inv = 1.f / (pl[h * 2048 + row] + pl[24576 + h * 2048 + row]);
    s16x8 a = *(const s16x8*)(pa + base);
    s16x8 b = *(const s16x8*)(pb + base);
    s16x8 o;
#pragma unroll
    for (int e = 0; e < 8; ++e)
        o[e] = (short)f2bf((bf2f((u16)a[e]) + bf2f((u16)b[e])) * inv);
    *(s16x8*)(obuf + base) = o;
}

// ---------- CA attention ----------
__global__ __launch_bounds__(256) void ca_attn(const float* __restrict__ qb,
                                               const float* __restrict__ kca,
                                               const float* __restrict__ vca,
                                               u16* __restrict__ obuf) {
    int wid = blockIdx.x * 4 + (threadIdx.x >> 6);
    int lane = threadIdx.x & 63;
    int n = wid / 12, h = wid % 12;
    float qd = qb[(size_t)n * 768 + h * 64 + lane] * 0.125f;
    float s[16];
#pragma unroll
    for (int j = 0; j < 16; ++j) {
        float part = qd * kca[(size_t)j * 768 + h * 64 + lane];
        s[j] = wave_sum(part);
    }
    float mm = s[0];
#pragma unroll
    for (int j = 1; j < 16; ++j) mm = fmaxf(mm, s[j]);
    float l = 0.f;
#pragma unroll
    for (int j = 0; j < 16; ++j) { s[j] = __expf(s[j] - mm); l += s[j]; }
    float od = 0.f;
#pragma unroll
    for (int j = 0; j < 16; ++j) od += s[j] * vca[(size_t)j * 768 + h * 64 + lane];
    obuf[(size_t)n * 768 + h * 64 + lane] = f2bf(od / l);
}

// ---------- CA q: RMSNorm + RoPE in place on qbuf f32 [2048][768] ----------
__global__ __launch_bounds__(256) void caq_rmsrope(float* __restrict__ qb,
                                                   const float* __restrict__ qnw,
                                                   const float* __restrict__ cosT,
                                                   const float* __restrict__ sinT) {
    int wid = blockIdx.x * 4 + (threadIdx.x >> 6);
    int lane = threadIdx.x & 63;
    int n = wid / 12, h = wid % 12;
    float* p = qb + (size_t)n * 768 + h * 64 + lane;
    float v = *p;
    float ss = wave_sum(v * v);
    float vn = v * rsqrtf(ss * (1.f / 64.f) + 1e-6f) * qnw[lane];
    float part = __shfl_xor(vn, 32);
    float rot = (lane < 32) ? -part : part;
    *p = vn * cosT[n * 64 + lane] + rot * sinT[n * 64 + lane];
}

// ---------- CA k: RMSNorm only, in place on kca [16][768] ----------
__global__ __launch_bounds__(256) void cak_rms(float* __restrict__ kca,
                                               const float* __restrict__ knw) {
    int wid = blockIdx.x * 4 + (threadIdx.x >> 6);  // 0..191
    int lane = threadIdx.x & 63;
    int n = wid / 12, h = wid % 12;
    float* p = kca + (size_t)n * 768 + h * 64 + lane;
    float v = *p;
    float ss = wave_sum(v * v);
    *p = v * rsqrtf(ss * (1.f / 64.f) + 1e-6f) * knw[lane];
}

// ---------- CA k/v small GEMM: [16,768] = cn[16,768] @ W[768,768]^T ----------
__global__ __launch_bounds__(256) void small_gemm_nt(const float* __restrict__ cn,
                                                     const float* __restrict__ cakw,
                                                     const float* __restrict__ cavw,
                                                     float* __restrict__ kca,
                                                     float* __restrict__ vca) {
    int wid = blockIdx.x * 4 + (threadIdx.x >> 6);  // 0..24575
    int lane = threadIdx.x & 63;
    int which = wid / 12288;
    int rem = wid % 12288;
    int rrow = rem / 768;
    int ocol = rem % 768;
    const float* Wm = which ? cavw : cakw;
    float sum = 0.f;
#pragma unroll
    for (int i = 0; i < 12; ++i)
        sum += cn[(size_t)rrow * 768 + i * 64 + lane] * Wm[(size_t)ocol * 768 + i * 64 + lane];
    sum = wave_sum(sum);
    if (lane == 0) (which ? vca : kca)[(size_t)rrow * 768 + ocol] = sum;
}

// =======================================================================
extern "C" void kernel_launch(void* const* d_in, const int* in_sizes, int n_in,
                              void* d_out, int out_size, void* d_ws, size_t ws_size,
                              hipStream_t stream) {
    const float* x     = (const float*)d_in[0];
    const float* c     = (const float*)d_in[1];
    const float* cond  = (const float*)d_in[2];
    const float* cosT  = (const float*)d_in[3];
    const float* sinT  = (const float*)d_in[4];
    const float* n1w   = (const float*)d_in[5];
    const float* n2w   = (const float*)d_in[6];
    const float* n3w   = (const float*)d_in[7];
    const float* cnw   = (const float*)d_in[8];
    const float* saqkvw  = (const float*)d_in[9];
    const float* saprojw = (const float*)d_in[10];
    const float* saprojb = (const float*)d_in[11];
    const float* saqnw   = (const float*)d_in[12];
    const float* saknw   = (const float*)d_in[13];
    const float* caqw    = (const float*)d_in[14];
    const float* cakw    = (const float*)d_in[15];
    const float* cavw    = (const float*)d_in[16];
    const float* caprojw = (const float*)d_in[17];
    const float* caprojb = (const float*)d_in[18];
    const float* caqnw   = (const float*)d_in[19];
    const float* caknw   = (const float*)d_in[20];
    const float* w1      = (const float*)d_in[21];
    const float* w2      = (const float*)d_in[22];
    const float* w3      = (const float*)d_in[23];
    const float* adaw    = (const float*)d_in[24];
    const float* adab    = (const float*)d_in[25];
    float* out = (float*)d_out;
    char* ws = (char*)d_ws;

    // ws layout (bytes):
    float* mod  = (float*)ws;                      // 0      : 27,648
    u16* hbuf   = (u16*)(ws + 32768);              // 32,768 : 3,145,728 (2048x768 bf16)
    u16* obuf   = (u16*)(ws + 3178496);            //         3,145,728
    char* R1    = ws + 6324224;                    // 12,582,912 shared region
    u16* qkvb   = (u16*)R1;                        //   qkv bf16 [2048][2304] (9,437,184)
    u16* vTb    = (u16*)(R1 + 9437184);            //   V^T bf16 [12][64][2048] (3,145,728)
    float* qbuf = (float*)R1;                      //   CA q f32 [2048][768]
    u16* gbuf   = (u16*)R1;                        //   MLP gate bf16 [2048][3072]
    float* cn   = (float*)(ws + 18907136);         // 49,152
    float* kca  = (float*)(ws + 18956288);         // 49,152
    float* vca  = (float*)(ws + 19005440);         // 49,152
    u16* wbuf   = (u16*)(ws + 19054592);           // 4,718,592 rotating bf16 weights
    u16* po0    = hbuf;                            // attn split-0 partial (transient)
    u16* po1    = wbuf;                            // attn split-1 partial (transient)
    float* plb  = (float*)(ws + 22200320);         // l partials [2][12][2048] f32
    // total 23,773,184 B

    ada_gemm<<<1728, 256, 0, stream>>>(c, adaw, adab, mod);

    // ---- self-attention ----
    rms_mod<<<2048, 256, 0, stream>>>(x, n1w, mod, 0, hbuf);
    cvt_bf16<<<864, 256, 0, stream>>>(saqkvw, wbuf, 221184);
    // qkv: [2048,2304] = hbuf @ Wqkv^T; grid 18x16=288, chunk C=9,R=4,nxc=2
    gemm_bt3<1><<<288, 256, 0, stream>>>(hbuf, wbuf, 2048, 2304, 768,
                                         nullptr, qkvb, nullptr, nullptr, nullptr,
                                         9, 4, 2, 288, 768);
    saqk_rmsrope<<<12288, 256, 0, stream>>>(qkvb, saqnw, saknw, cosT, sinT);
    v_transpose<<<dim3(32, 12), 256, 0, stream>>>(qkvb, vTb);
    sa_attn_mfma<<<dim3(32, 12, 2), 256, 0, stream>>>(qkvb, vTb, po0, po1, plb);
    sa_combine<<<768, 256, 0, stream>>>(po0, po1, plb, obuf);
    cvt_bf16<<<288, 256, 0, stream>>>(saprojw, wbuf, 73728);
    // sa proj: split-K=2; init out = x + g*b, then atomic accumulate
    init_axpb<<<1536, 256, 0, stream>>>(x, mod + 2 * 768, saprojb, out);
    gemm_bt3<5><<<192, 256, 0, stream>>>(obuf, wbuf, 2048, 768, 768,
                                         out, nullptr, nullptr, mod + 2 * 768, nullptr,
                                         3, 4, 2, 96, 384);

    // ---- cross-attention ----
    rms_mod<<<2048, 256, 0, stream>>>(out, n2w, mod, 3, hbuf);
    cvt_bf16<<<288, 256, 0, stream>>>(caqw, wbuf, 73728);
    // ca q: split-K=2; init qbuf = 0, plain atomic accumulate
    init_axpb<<<1536, 256, 0, stream>>>(nullptr, nullptr, nullptr, qbuf);
    gemm_bt3<5><<<192, 256, 0, stream>>>(hbuf, wbuf, 2048, 768, 768,
                                         qbuf, nullptr, nullptr, nullptr, nullptr,
                                         3, 4, 2, 96, 384);
    rms_plain<<<16, 256, 0, stream>>>(cond, cnw, cn);
    small_gemm_nt<<<6144, 256, 0, stream>>>(cn, cakw, cavw, kca, vca);
    cak_rms<<<48, 256, 0, stream>>>(kca, caknw);
    caq_rmsrope<<<6144, 256, 0, stream>>>(qbuf, caqnw, cosT, sinT);
    ca_attn<<<6144, 256, 0, stream>>>(qbuf, kca, vca, obuf);
    cvt_bf16<<<288, 256, 0, stream>>>(caprojw, wbuf, 73728);
    // ca proj: split-K=2; init out += g*b (in-place resid), atomic accumulate
    init_axpb<<<1536, 256, 0, stream>>>(out, mod + 5 * 768, caprojb, out);
    gemm_bt3<5><<<192, 256, 0, stream>>>(obuf, wbuf, 2048, 768, 768,
                                         out, nullptr, nullptr, mod + 5 * 768, nullptr,
                                         3, 4, 2, 96, 384);

    // ---- SwiGLU MLP ----
    rms_mod<<<2048, 256, 0, stream>>>(out, n3w, mod, 6, hbuf);
    cvt_bf16<<<1152, 256, 0, stream>>>(w1, wbuf, 294912);
    // w1: grid 24x16=384, chunk C=6,R=8,nxc=4
    gemm_bt3<3><<<384, 256, 0, stream>>>(hbuf, wbuf, 2048, 3072, 768,
                                         nullptr, gbuf, nullptr, nullptr, nullptr,
                                         6, 8, 4, 384, 768);
    cvt_bf16<<<1152, 256, 0, stream>>>(w3, wbuf, 294912);
    gemm_bt3<4><<<384, 256, 0, stream>>>(hbuf, wbuf, 2048, 3072, 768,
                                         nullptr, gbuf, nullptr, nullptr, nullptr,
                                         6, 8, 4, 384, 768);
    cvt_bf16<<<1152, 256, 0, stream>>>(w2, wbuf, 294912);
    // w2: split-K=4 (K=3072 -> 768/slice); resid==out already holds x, bias none
    gemm_bt3<5><<<384, 256, 0, stream>>>(gbuf, wbuf, 2048, 768, 3072,
                                         out, nullptr, nullptr, mod + 8 * 768, nullptr,
                                         3, 4, 2, 96, 768);
}

// Round 8
// 316.352 us; speedup vs baseline: 1.1093x; 1.1093x over previous
//
#include <hip/hip_runtime.h>

typedef unsigned short u16;
typedef unsigned int u32;
typedef __attribute__((ext_vector_type(8))) short s16x8;
typedef __attribute__((ext_vector_type(4))) float f32x4;
typedef __attribute__((ext_vector_type(4))) int i32x4;

// ---------- bf16 helpers (bit-level, RNE) ----------
static __device__ __forceinline__ float bf2f(u16 u) {
    return __uint_as_float(((u32)u) << 16);
}
static __device__ __forceinline__ u16 f2bf(float f) {
    u32 x = __float_as_uint(f);
    return (u16)((x + 0x7fffu + ((x >> 16) & 1u)) >> 16);
}
static __device__ __forceinline__ i32x4 pack8(float4 a, float4 b) {
    u32 p0 = (u32)f2bf(a.x) | ((u32)f2bf(a.y) << 16);
    u32 p1 = (u32)f2bf(a.z) | ((u32)f2bf(a.w) << 16);
    u32 p2 = (u32)f2bf(b.x) | ((u32)f2bf(b.y) << 16);
    u32 p3 = (u32)f2bf(b.z) | ((u32)f2bf(b.w) << 16);
    return (i32x4){(int)p0, (int)p1, (int)p2, (int)p3};
}
static __device__ __forceinline__ float wave_sum(float v) {
#pragma unroll
    for (int off = 32; off > 0; off >>= 1) v += __shfl_xor(v, off);
    return v;
}
// async global->LDS, 16B per lane; dest is wave-uniform base (+lane*16 by HW)
static __device__ __forceinline__ void gload16(const u16* g, void* l) {
    __builtin_amdgcn_global_load_lds((const __attribute__((address_space(1))) void*)g,
                                     (__attribute__((address_space(3))) void*)l, 16, 0, 0);
}

// ---------- fp32 -> bf16 weight conversion (8 elems/thread) ----------
__global__ __launch_bounds__(256) void cvt_bf16(const float* __restrict__ src,
                                                u16* __restrict__ dst, int n8) {
    int i = blockIdx.x * 256 + threadIdx.x;
    if (i >= n8) return;
    float4 a = *(const float4*)(src + (size_t)i * 8);
    float4 b = *(const float4*)(src + (size_t)i * 8 + 4);
    *(i32x4*)(dst + (size_t)i * 8) = pack8(a, b);
}

// ---------- adaLN: mod = silu(c) @ ada_w.T + ada_b ----------
__global__ __launch_bounds__(256) void ada_gemm(const float* __restrict__ c,
                                                const float* __restrict__ adaw,
                                                const float* __restrict__ adab,
                                                float* __restrict__ mod) {
    int wid = blockIdx.x * 4 + (threadIdx.x >> 6);
    int lane = threadIdx.x & 63;
    float sum = 0.f;
#pragma unroll
    for (int i = 0; i < 12; ++i) {
        float cv = c[i * 64 + lane];
        cv = cv / (1.f + __expf(-cv));
        sum += cv * adaw[(size_t)wid * 768 + i * 64 + lane];
    }
    sum = wave_sum(sum);
    if (lane == 0) mod[wid] = sum + adab[wid];
}

// ---------- fused RMSNorm + modulate, writes bf16 ----------
__global__ __launch_bounds__(256) void rms_mod(const float* __restrict__ x,
                                               const float* __restrict__ w,
                                               const float* __restrict__ mod, int chunk,
                                               u16* __restrict__ out) {
    const int row = blockIdx.x;
    const int tid = threadIdx.x;
    const float* xr = x + (size_t)row * 768;
    float v0 = xr[tid], v1 = xr[256 + tid], v2 = xr[512 + tid];
    float ss = wave_sum(v0 * v0 + v1 * v1 + v2 * v2);
    __shared__ float red[4];
    if ((tid & 63) == 0) red[tid >> 6] = ss;
    __syncthreads();
    float rn = rsqrtf((red[0] + red[1] + red[2] + red[3]) * (1.f / 768.f) + 1e-6f);
    const float* sh = mod + chunk * 768;
    const float* sc = sh + 768;
    u16* orow = out + (size_t)row * 768;
    orow[tid]       = f2bf(v0 * rn * w[tid]       * (1.f + sc[tid])       + sh[tid]);
    orow[256 + tid] = f2bf(v1 * rn * w[256 + tid] * (1.f + sc[256 + tid]) + sh[256 + tid]);
    orow[512 + tid] = f2bf(v2 * rn * w[512 + tid] * (1.f + sc[512 + tid]) + sh[512 + tid]);
}

// ---------- plain RMSNorm (cond), fp32 out ----------
__global__ __launch_bounds__(256) void rms_plain(const float* __restrict__ x,
                                                 const float* __restrict__ w,
                                                 float* __restrict__ out) {
    const int row = blockIdx.x;
    const int tid = threadIdx.x;
    const float* xr = x + (size_t)row * 768;
    float v0 = xr[tid], v1 = xr[256 + tid], v2 = xr[512 + tid];
    float ss = wave_sum(v0 * v0 + v1 * v1 + v2 * v2);
    __shared__ float red[4];
    if ((tid & 63) == 0) red[tid >> 6] = ss;
    __syncthreads();
    float rn = rsqrtf((red[0] + red[1] + red[2] + red[3]) * (1.f / 768.f) + 1e-6f);
    float* orow = out + (size_t)row * 768;
    orow[tid]       = v0 * rn * w[tid];
    orow[256 + tid] = v1 * rn * w[256 + tid];
    orow[512 + tid] = v2 * rn * w[512 + tid];
}

// ---------- MFMA bf16 GEMM v4: 256 thr, 128xBN tile, BK=32, XCD swizzle ----------
// C[M,N] = A[M,K](bf16) @ Wb[N,K](bf16)^T. 4 waves (2x2), per-wave 64x(BN/2).
// XCD swizzle: xcd = bid&7 owns a CxR chunk of the (ncolx nrow) tile grid.
// EPI 0: f32 out. 1: bf16 out. 2: out = resid + gate[col]*(acc+bias[col]).
// 3: bf16(silu(acc)). 4: outb RMW *= acc.
template <int EPI, int BN>
__global__ __launch_bounds__(256) void gemm_bt4(const u16* __restrict__ A,
                                                const u16* __restrict__ Wb,
                                                int M, int N, int K,
                                                float* outf, u16* outb,
                                                const float* resid,
                                                const float* __restrict__ gate,
                                                const float* __restrict__ bias,
                                                int C, int R, int nxc) {
    constexpr int NB = BN / 32;  // acc cols per wave (4 or 2)
    __shared__ __align__(16) u16 As[2][128 * 32];
    __shared__ __align__(16) u16 Bs[2][BN * 32];
    const int tid = threadIdx.x;
    const int lane = tid & 63;
    const int w = tid >> 6;
    const int wr = w >> 1, wc = w & 1;
    const int sub = blockIdx.x;
    const int xcd = sub & 7, idx = sub >> 3;
    const int cx = xcd % nxc, cy = xcd / nxc;
    const int col0 = (cx * C + idx % C) * BN;
    const int row0 = (cy * R + idx / C) << 7;

    // staging source pointers (inverse-XOR-preswizzled; linear LDS dest)
    const int r0u = tid >> 2, s0u = (tid & 3) ^ (r0u & 3);
    const int r1u = (tid + 256) >> 2, s1u = (tid & 3) ^ (r1u & 3);
    const u16* a0 = A + (size_t)(row0 + r0u) * K + s0u * 8;
    const u16* a1 = A + (size_t)(row0 + r1u) * K + s1u * 8;
    const u16* b0 = Wb + (size_t)(col0 + r0u) * K + s0u * 8;
    const u16* b1 = Wb + (size_t)(col0 + r1u) * K + s1u * 8;  // unused for BN=64

    f32x4 acc[4][NB];
#pragma unroll
    for (int m = 0; m < 4; ++m)
#pragma unroll
        for (int n = 0; n < NB; ++n) acc[m][n] = (f32x4){0.f, 0.f, 0.f, 0.f};

    const int nt = K >> 5;
    int cur = 0;
#define G4_STAGE(buf, k0)                                   \
    {                                                       \
        char* ad = (char*)As[buf] + w * 1024;               \
        char* bd = (char*)Bs[buf] + w * 1024;               \
        gload16(a0 + (k0), ad);                             \
        gload16(a1 + (k0), ad + 4096);                      \
        gload16(b0 + (k0), bd);                             \
        if constexpr (BN == 128) gload16(b1 + (k0), bd + 4096); \
    }
    G4_STAGE(0, 0)
    for (int t = 0; t < nt; ++t) {
        __syncthreads();  // tile t staged; buf cur^1 free
        if (t + 1 < nt) G4_STAGE(cur ^ 1, (t + 1) << 5)
        s16x8 af[4], bfv[NB];
#pragma unroll
        for (int m = 0; m < 4; ++m) {
            int ra = wr * 64 + m * 16 + (lane & 15);
            int u = (lane >> 4) ^ (ra & 3);
            af[m] = *(const s16x8*)((const char*)As[cur] + ra * 64 + u * 16);
        }
#pragma unroll
        for (int n = 0; n < NB; ++n) {
            int cb = wc * (BN / 2) + n * 16 + (lane & 15);
            int u = (lane >> 4) ^ (cb & 3);
            bfv[n] = *(const s16x8*)((const char*)Bs[cur] + cb * 64 + u * 16);
        }
#pragma unroll
        for (int m = 0; m < 4; ++m)
#pragma unroll
            for (int n = 0; n < NB; ++n)
                acc[m][n] = __builtin_amdgcn_mfma_f32_16x16x32_bf16(af[m], bfv[n], acc[m][n], 0, 0, 0);
        cur ^= 1;
    }
#undef G4_STAGE
    // epilogue: C frag map col=lane&15, row=(lane>>4)*4+i (HW-verified)
#pragma unroll
    for (int m = 0; m < 4; ++m) {
#pragma unroll
        for (int n = 0; n < NB; ++n) {
#pragma unroll
            for (int i = 0; i < 4; ++i) {
                int r = row0 + wr * 64 + m * 16 + (lane >> 4) * 4 + i;
                int cc = col0 + wc * (BN / 2) + n * 16 + (lane & 15);
                size_t idx2 = (size_t)r * N + cc;
                float v = acc[m][n][i];
                if constexpr (EPI == 0) {
                    outf[idx2] = v;
                } else if constexpr (EPI == 1) {
                    outb[idx2] = f2bf(v);
                } else if constexpr (EPI == 2) {
                    float b = bias ? bias[cc] : 0.f;
                    outf[idx2] = resid[idx2] + gate[cc] * (v + b);
                } else if constexpr (EPI == 3) {
                    outb[idx2] = f2bf(v / (1.f + __expf(-v)));
                } else if constexpr (EPI == 4) {
                    outb[idx2] = f2bf(v * bf2f(outb[idx2]));
                }
            }
        }
    }
}

// ---------- SA q/k: RMSNorm(head) + RoPE, in place on qkv bf16 ----------
__global__ __launch_bounds__(256) void saqk_rmsrope(u16* __restrict__ qkv,
                                                    const float* __restrict__ qnw,
                                                    const float* __restrict__ knw,
                                                    const float* __restrict__ cosT,
                                                    const float* __restrict__ sinT) {
    int wid = blockIdx.x * 4 + (threadIdx.x >> 6);  // 0..49151
    int lane = threadIdx.x & 63;
    int n = wid / 24;
    int rem = wid % 24;
    int which = rem / 12;  // 0=q 1=k
    int h = rem % 12;
    u16* p = qkv + (size_t)n * 2304 + which * 768 + h * 64 + lane;
    float v = bf2f(*p);
    float ss = wave_sum(v * v);
    const float* wv = which ? knw : qnw;
    float vn = v * rsqrtf(ss * (1.f / 64.f) + 1e-6f) * wv[lane];
    float part = __shfl_xor(vn, 32);
    float rot = (lane < 32) ? -part : part;
    *p = f2bf(vn * cosT[n * 64 + lane] + rot * sinT[n * 64 + lane]);
}

// ---------- V transpose: qkv V part [2048][12*64] -> vT [12][64][2048] ----------
__global__ __launch_bounds__(256) void v_transpose(const u16* __restrict__ qkv,
                                                   u16* __restrict__ vT) {
    const int kt = blockIdx.x, h = blockIdx.y;
    const int tid = threadIdx.x;
    __shared__ __align__(16) u16 tt[64][72];  // +8 pad breaks bank conflicts
    {
        int key = tid >> 2, qq = tid & 3;
        const u16* src = qkv + (size_t)(kt * 64 + key) * 2304 + 1536 + h * 64 + qq * 16;
        *(i32x4*)&tt[key][qq * 16]     = *(const i32x4*)src;
        *(i32x4*)&tt[key][qq * 16 + 8] = *(const i32x4*)(src + 8);
    }
    __syncthreads();
    {
        int d = tid >> 2, kq = tid & 3;
        s16x8 o0, o1;
#pragma unroll
        for (int e = 0; e < 8; ++e) o0[e] = (short)tt[kq * 16 + e][d];
#pragma unroll
        for (int e = 0; e < 8; ++e) o1[e] = (short)tt[kq * 16 + 8 + e][d];
        u16* dst = vT + (size_t)h * 131072 + (size_t)d * 2048 + kt * 64 + kq * 16;
        *(s16x8*)dst = o0;
        *(s16x8*)(dst + 8) = o1;
    }
}

// ---------- SA flash attention, MFMA bf16, FIXED-MAX softmax + 2-way key split ----------
__global__ __launch_bounds__(256) void sa_attn_mfma(const u16* __restrict__ qkv,
                                                    const u16* __restrict__ vT,
                                                    u16* __restrict__ po0,
                                                    u16* __restrict__ po1,
                                                    float* __restrict__ pl) {
    const int h = blockIdx.y;
    const int r0 = blockIdx.x * 64;
    const int z = blockIdx.z;  // key split
    const int tid = threadIdx.x;
    const int lane = tid & 63;
    const int w = tid >> 6;
    __shared__ __align__(16) u16 Ks[2][64 * 64];
    __shared__ __align__(16) u16 Vs[2][64 * 64];
    __shared__ __align__(16) u16 Ps[4][16 * 64];

    s16x8 qf[2];
    {
        const u16* qrow = qkv + (size_t)(r0 + w * 16 + (lane & 15)) * 2304 + h * 64 + ((lane >> 4) * 8);
        qf[0] = *(const s16x8*)qrow;
        qf[1] = *(const s16x8*)(qrow + 32);
    }
    f32x4 oacc[4];
#pragma unroll
    for (int n = 0; n < 4; ++n) oacc[n] = (f32x4){0.f, 0.f, 0.f, 0.f};
    float lp[4] = {0.f, 0.f, 0.f, 0.f};

    const u16* ksrc[2];
    const u16* vsrc[2];
#pragma unroll
    for (int j = 0; j < 2; ++j) {
        int u = (w * 2 + j) * 64 + lane;
        int row = u >> 3, seg = (u & 7) ^ (row & 7);
        ksrc[j] = qkv + (size_t)(z * 1024 + row) * 2304 + 768 + h * 64 + seg * 8;
        vsrc[j] = vT + (size_t)h * 131072 + (size_t)row * 2048 + z * 1024 + seg * 8;
    }

#define SA_STAGE(buf, t_)                                          \
    {                                                              \
        char* kd = (char*)Ks[buf] + w * 2048;                      \
        char* vd = (char*)Vs[buf] + w * 2048;                      \
        gload16(ksrc[0] + (size_t)(t_) * 147456, kd);              \
        gload16(ksrc[1] + (size_t)(t_) * 147456, kd + 1024);       \
        gload16(vsrc[0] + (t_) * 64, vd);                          \
        gload16(vsrc[1] + (t_) * 64, vd + 1024);                   \
    }

    SA_STAGE(0, 0)
    int cur = 0;
    for (int t = 0; t < 16; ++t) {
        __syncthreads();
        if (t + 1 < 16) SA_STAGE(cur ^ 1, t + 1)

        f32x4 sacc[4];
#pragma unroll
        for (int n = 0; n < 4; ++n) sacc[n] = (f32x4){0.f, 0.f, 0.f, 0.f};
#pragma unroll
        for (int kk = 0; kk < 2; ++kk) {
#pragma unroll
            for (int n = 0; n < 4; ++n) {
                int key = n * 16 + (lane & 15);
                int d = kk * 32 + (lane >> 4) * 8;
                int boff = key * 128 + ((d * 2) ^ ((key & 7) << 4));
                s16x8 kf = *(const s16x8*)((const char*)Ks[cur] + boff);
                sacc[n] = __builtin_amdgcn_mfma_f32_16x16x32_bf16(qf[kk], kf, sacc[n], 0, 0, 0);
            }
        }
        // fixed-max softmax: p = exp(s*0.125 - 8); |s*0.125| <= 8 by Cauchy-Schwarz
#pragma unroll
        for (int n = 0; n < 4; ++n) {
#pragma unroll
            for (int i = 0; i < 4; ++i) {
                float p = __expf(fmaf(sacc[n][i], 0.125f, -8.0f));
                lp[i] += p;
                int row = (lane >> 4) * 4 + i;
                int key = n * 16 + (lane & 15);
                int boff = row * 128 + ((key * 2) ^ ((row & 7) << 4));
                *(u16*)((char*)Ps[w] + boff) = f2bf(p);
            }
        }
#pragma unroll
        for (int kk = 0; kk < 2; ++kk) {
            int koff = kk * 32 + (lane >> 4) * 8;
            int prow = lane & 15;
            int pboff = prow * 128 + ((koff * 2) ^ ((prow & 7) << 4));
            s16x8 pf = *(const s16x8*)((const char*)Ps[w] + pboff);
#pragma unroll
            for (int n = 0; n < 4; ++n) {
                int d = n * 16 + (lane & 15);
                int vboff = d * 128 + ((koff * 2) ^ ((d & 7) << 4));
                s16x8 vf = *(const s16x8*)((const char*)Vs[cur] + vboff);
                oacc[n] = __builtin_amdgcn_mfma_f32_16x16x32_bf16(pf, vf, oacc[n], 0, 0, 0);
            }
        }
        cur ^= 1;
    }
#undef SA_STAGE
#pragma unroll
    for (int off = 1; off < 16; off <<= 1) {
#pragma unroll
        for (int i = 0; i < 4; ++i) lp[i] += __shfl_xor(lp[i], off);
    }
    u16* po = z ? po1 : po0;
#pragma unroll
    for (int n = 0; n < 4; ++n) {
#pragma unroll
        for (int i = 0; i < 4; ++i) {
            int r = r0 + w * 16 + (lane >> 4) * 4 + i;
            int d = n * 16 + (lane & 15);
            po[(size_t)r * 768 + h * 64 + d] = f2bf(oacc[n][i]);
        }
    }
    if ((lane & 15) == 0) {
#pragma unroll
        for (int i = 0; i < 4; ++i) {
            int r = r0 + w * 16 + (lane >> 4) * 4 + i;
            pl[z * 24576 + h * 2048 + r] = lp[i];
        }
    }
}

// ---------- combine the two key-split partials: O = (Oa+Ob)/(la+lb) ----------
__global__ __launch_bounds__(256) void sa_combine(const u16* __restrict__ pa,
                                                  const u16* __restrict__ pb,
                                                  const float* __restrict__ pl,
                                                  u16* __restrict__ obuf) {
    int idx = blockIdx.x * 256 + threadIdx.x;  // 8-elem units
    int base = idx * 8;
    int row = base / 768;
    int col = base % 768;
    int h = col >> 6;
    float inv = 1.f / (pl[h * 2048 + row] + pl[24576 + h * 2048 + row]);
    s16x8 a = *(const s16x8*)(pa + base);
    s16x8 b = *(const s16x8*)(pb + base);
    s16x8 o;
#pragma unroll
    for (int e = 0; e < 8; ++e)
        o[e] = (short)f2bf((bf2f((u16)a[e]) + bf2f((u16)b[e])) * inv);
    *(s16x8*)(obuf + base) = o;
}

// ---------- CA attention ----------
__global__ __launch_bounds__(256) void ca_attn(const float* __restrict__ qb,
                                               const float* __restrict__ kca,
                                               const float* __restrict__ vca,
                                               u16* __restrict__ obuf) {
    int wid = blockIdx.x * 4 + (threadIdx.x >> 6);
    int lane = threadIdx.x & 63;
    int n = wid / 12, h = wid % 12;
    float qd = qb[(size_t)n * 768 + h * 64 + lane] * 0.125f;
    float s[16];
#pragma unroll
    for (int j = 0; j < 16; ++j) {
        float part = qd * kca[(size_t)j * 768 + h * 64 + lane];
        s[j] = wave_sum(part);
    }
    float mm = s[0];
#pragma unroll
    for (int j = 1; j < 16; ++j) mm = fmaxf(mm, s[j]);
    float l = 0.f;
#pragma unroll
    for (int j = 0; j < 16; ++j) { s[j] = __expf(s[j] - mm); l += s[j]; }
    float od = 0.f;
#pragma unroll
    for (int j = 0; j < 16; ++j) od += s[j] * vca[(size_t)j * 768 + h * 64 + lane];
    obuf[(size_t)n * 768 + h * 64 + lane] = f2bf(od / l);
}

// ---------- CA q: RMSNorm + RoPE in place on qbuf f32 [2048][768] ----------
__global__ __launch_bounds__(256) void caq_rmsrope(float* __restrict__ qb,
                                                   const float* __restrict__ qnw,
                                                   const float* __restrict__ cosT,
                                                   const float* __restrict__ sinT) {
    int wid = blockIdx.x * 4 + (threadIdx.x >> 6);
    int lane = threadIdx.x & 63;
    int n = wid / 12, h = wid % 12;
    float* p = qb + (size_t)n * 768 + h * 64 + lane;
    float v = *p;
    float ss = wave_sum(v * v);
    float vn = v * rsqrtf(ss * (1.f / 64.f) + 1e-6f) * qnw[lane];
    float part = __shfl_xor(vn, 32);
    float rot = (lane < 32) ? -part : part;
    *p = vn * cosT[n * 64 + lane] + rot * sinT[n * 64 + lane];
}

// ---------- CA k: RMSNorm only, in place on kca [16][768] ----------
__global__ __launch_bounds__(256) void cak_rms(float* __restrict__ kca,
                                               const float* __restrict__ knw) {
    int wid = blockIdx.x * 4 + (threadIdx.x >> 6);  // 0..191
    int lane = threadIdx.x & 63;
    int n = wid / 12, h = wid % 12;
    float* p = kca + (size_t)n * 768 + h * 64 + lane;
    float v = *p;
    float ss = wave_sum(v * v);
    *p = v * rsqrtf(ss * (1.f / 64.f) + 1e-6f) * knw[lane];
}

// ---------- CA k/v small GEMM: [16,768] = cn[16,768] @ W[768,768]^T ----------
__global__ __launch_bounds__(256) void small_gemm_nt(const float* __restrict__ cn,
                                                     const float* __restrict__ cakw,
                                                     const float* __restrict__ cavw,
                                                     float* __restrict__ kca,
                                                     float* __restrict__ vca) {
    int wid = blockIdx.x * 4 + (threadIdx.x >> 6);  // 0..24575
    int lane = threadIdx.x & 63;
    int which = wid / 12288;
    int rem = wid % 12288;
    int rrow = rem / 768;
    int ocol = rem % 768;
    const float* Wm = which ? cavw : cakw;
    float sum = 0.f;
#pragma unroll
    for (int i = 0; i < 12; ++i)
        sum += cn[(size_t)rrow * 768 + i * 64 + lane] * Wm[(size_t)ocol * 768 + i * 64 + lane];
    sum = wave_sum(sum);
    if (lane == 0) (which ? vca : kca)[(size_t)rrow * 768 + ocol] = sum;
}

// =======================================================================
extern "C" void kernel_launch(void* const* d_in, const int* in_sizes, int n_in,
                              void* d_out, int out_size, void* d_ws, size_t ws_size,
                              hipStream_t stream) {
    const float* x     = (const float*)d_in[0];
    const float* c     = (const float*)d_in[1];
    const float* cond  = (const float*)d_in[2];
    const float* cosT  = (const float*)d_in[3];
    const float* sinT  = (const float*)d_in[4];
    const float* n1w   = (const float*)d_in[5];
    const float* n2w   = (const float*)d_in[6];
    const float* n3w   = (const float*)d_in[7];
    const float* cnw   = (const float*)d_in[8];
    const float* saqkvw  = (const float*)d_in[9];
    const float* saprojw = (const float*)d_in[10];
    const float* saprojb = (const float*)d_in[11];
    const float* saqnw   = (const float*)d_in[12];
    const float* saknw   = (const float*)d_in[13];
    const float* caqw    = (const float*)d_in[14];
    const float* cakw    = (const float*)d_in[15];
    const float* cavw    = (const float*)d_in[16];
    const float* caprojw = (const float*)d_in[17];
    const float* caprojb = (const float*)d_in[18];
    const float* caqnw   = (const float*)d_in[19];
    const float* caknw   = (const float*)d_in[20];
    const float* w1      = (const float*)d_in[21];
    const float* w2      = (const float*)d_in[22];
    const float* w3      = (const float*)d_in[23];
    const float* adaw    = (const float*)d_in[24];
    const float* adab    = (const float*)d_in[25];
    float* out = (float*)d_out;
    char* ws = (char*)d_ws;

    // ws layout (bytes):
    float* mod  = (float*)ws;                      // 0      : 27,648
    u16* hbuf   = (u16*)(ws + 32768);              // 32,768 : 3,145,728 (2048x768 bf16)
    u16* obuf   = (u16*)(ws + 3178496);            //         3,145,728
    char* R1    = ws + 6324224;                    // 12,582,912 shared region
    u16* qkvb   = (u16*)R1;                        //   qkv bf16 [2048][2304] (9,437,184)
    u16* vTb    = (u16*)(R1 + 9437184);            //   V^T bf16 [12][64][2048] (3,145,728)
    float* qbuf = (float*)R1;                      //   CA q f32 [2048][768]
    u16* gbuf   = (u16*)R1;                        //   MLP gate bf16 [2048][3072]
    float* cn   = (float*)(ws + 18907136);         // 49,152
    float* kca  = (float*)(ws + 18956288);         // 49,152
    float* vca  = (float*)(ws + 19005440);         // 49,152
    u16* wbuf   = (u16*)(ws + 19054592);           // 4,718,592 rotating bf16 weights
    u16* po0    = hbuf;                            // attn split-0 partial (transient)
    u16* po1    = wbuf;                            // attn split-1 partial (transient)
    float* plb  = (float*)(ws + 22200320);         // l partials [2][12][2048] f32
    // total 23,773,184 B

    ada_gemm<<<1728, 256, 0, stream>>>(c, adaw, adab, mod);

    // ---- self-attention ----
    rms_mod<<<2048, 256, 0, stream>>>(x, n1w, mod, 0, hbuf);
    cvt_bf16<<<864, 256, 0, stream>>>(saqkvw, wbuf, 221184);
    // qkv: [2048,2304]; tiles 18x16=288; XCD chunks C=9,R=4,nxc=2
    gemm_bt4<1, 128><<<288, 256, 0, stream>>>(hbuf, wbuf, 2048, 2304, 768,
                                              nullptr, qkvb, nullptr, nullptr, nullptr,
                                              9, 4, 2);
    saqk_rmsrope<<<12288, 256, 0, stream>>>(qkvb, saqnw, saknw, cosT, sinT);
    v_transpose<<<dim3(32, 12), 256, 0, stream>>>(qkvb, vTb);
    sa_attn_mfma<<<dim3(32, 12, 2), 256, 0, stream>>>(qkvb, vTb, po0, po1, plb);
    sa_combine<<<768, 256, 0, stream>>>(po0, po1, plb, obuf);
    cvt_bf16<<<288, 256, 0, stream>>>(saprojw, wbuf, 73728);
    // sa proj: [2048,768]; BN=64 tiles 12x16=192; chunks C=6,R=4,nxc=2
    gemm_bt4<2, 64><<<192, 256, 0, stream>>>(obuf, wbuf, 2048, 768, 768,
                                             out, nullptr, x, mod + 2 * 768, saprojb,
                                             6, 4, 2);

    // ---- cross-attention ----
    rms_mod<<<2048, 256, 0, stream>>>(out, n2w, mod, 3, hbuf);
    cvt_bf16<<<288, 256, 0, stream>>>(caqw, wbuf, 73728);
    gemm_bt4<0, 64><<<192, 256, 0, stream>>>(hbuf, wbuf, 2048, 768, 768,
                                             qbuf, nullptr, nullptr, nullptr, nullptr,
                                             6, 4, 2);
    rms_plain<<<16, 256, 0, stream>>>(cond, cnw, cn);
    small_gemm_nt<<<6144, 256, 0, stream>>>(cn, cakw, cavw, kca, vca);
    cak_rms<<<48, 256, 0, stream>>>(kca, caknw);
    caq_rmsrope<<<6144, 256, 0, stream>>>(qbuf, caqnw, cosT, sinT);
    ca_attn<<<6144, 256, 0, stream>>>(qbuf, kca, vca, obuf);
    cvt_bf16<<<288, 256, 0, stream>>>(caprojw, wbuf, 73728);
    // ca proj: resid == out in-place (each element read+written once by its owner)
    gemm_bt4<2, 64><<<192, 256, 0, stream>>>(obuf, wbuf, 2048, 768, 768,
                                             out, nullptr, out, mod + 5 * 768, caprojb,
                                             6, 4, 2);

    // ---- SwiGLU MLP ----
    rms_mod<<<2048, 256, 0, stream>>>(out, n3w, mod, 6, hbuf);
    cvt_bf16<<<1152, 256, 0, stream>>>(w1, wbuf, 294912);
    // w1: [2048,3072]; tiles 24x16=384; chunks C=6,R=8,nxc=4
    gemm_bt4<3, 128><<<384, 256, 0, stream>>>(hbuf, wbuf, 2048, 3072, 768,
                                              nullptr, gbuf, nullptr, nullptr, nullptr,
                                              6, 8, 4);
    cvt_bf16<<<1152, 256, 0, stream>>>(w3, wbuf, 294912);
    gemm_bt4<4, 128><<<384, 256, 0, stream>>>(hbuf, wbuf, 2048, 3072, 768,
                                              nullptr, gbuf, nullptr, nullptr, nullptr,
                                              6, 8, 4);
    cvt_bf16<<<1152, 256, 0, stream>>>(w2, wbuf, 294912);
    // w2: [2048,768], K=3072; BN=64; resid == out (holds x after CA)
    gemm_bt4<2, 64><<<192, 256, 0, stream>>>(gbuf, wbuf, 2048, 768, 3072,
                                             out, nullptr, out, mod + 8 * 768, nullptr,
                                             6, 4, 2);
}